// Round 3
// baseline (1581.529 us; speedup 1.0000x reference)
//
#include <hip/hip_runtime.h>

// Sparse graph attention (fp32), single fused edge pass + node normalize.
// 16 lanes per edge (4 edges per 64-lane wave), float4 per lane:
//   lane sub in [0,16): loads q[i0][4*sub..+3], k[i1][...] as float4 (16B),
//   eigs as float2, dot reduced over the 16-lane group via shfl_xor {1,2,4,8}.
//   e = min(exp(dot/8 + exp(l0)*eig_dot), 5)
//   denom[i0] += e (atomic, sub==0); out[i0][:] += e*v[i1][:] (4 atomics/lane)
// then out[r,:] /= (denom[r]==0 ? 1 : denom[r]).
//
// vs wave-per-edge: ~4x fewer VALU + VMEM instructions per edge, same bytes.

#define HD 64
#define ED 32

__global__ void edge_fused_kernel(const float* __restrict__ q,
                                  const float* __restrict__ k,
                                  const float* __restrict__ v,
                                  const float* __restrict__ eigs,
                                  const float* __restrict__ lambda0,
                                  const int* __restrict__ idx,
                                  float* __restrict__ denom,
                                  float* __restrict__ out,
                                  int n_edges) {
    long long gid = (long long)blockIdx.x * blockDim.x + threadIdx.x;
    int edge = (int)(gid >> 4);        // 16 lanes per edge
    int sub  = (int)(gid & 15);
    if (edge >= n_edges) return;

    int i0 = idx[edge];            // destination (row)
    int i1 = idx[n_edges + edge];  // source (col)

    const float expL = __expf(lambda0[0]);

    // 16B vector gathers: q row i0, k row i1
    const float4* q4 = (const float4*)(q + (long long)i0 * HD);
    const float4* k4 = (const float4*)(k + (long long)i1 * HD);
    float4 qa = q4[sub];
    float4 kb = k4[sub];
    float c = qa.x * kb.x + qa.y * kb.y + qa.z * kb.z + qa.w * kb.w;
    c *= 0.125f;   // 1/sqrt(64)

    // eigs: 32 floats -> float2 per lane
    const float2* ea2 = (const float2*)(eigs + (long long)i0 * ED);
    const float2* eb2 = (const float2*)(eigs + (long long)i1 * ED);
    float2 ea = ea2[sub];
    float2 eb = eb2[sub];
    c += expL * (ea.x * eb.x + ea.y * eb.y);

    // reduce over the 16-lane group (xor offsets stay inside the group)
    #pragma unroll
    for (int off = 8; off > 0; off >>= 1)
        c += __shfl_xor(c, off, 64);

    float e = fminf(__expf(c), 5.0f);   // exp>0, only the upper clip binds

    if (sub == 0) atomicAdd(&denom[i0], e);

    // v gather (16B) + scatter 4 atomics per lane
    const float4* v4 = (const float4*)(v + (long long)i1 * HD);
    float4 vv = v4[sub];
    float* orow = out + (long long)i0 * HD + sub * 4;
    atomicAdd(orow + 0, e * vv.x);
    atomicAdd(orow + 1, e * vv.y);
    atomicAdd(orow + 2, e * vv.z);
    atomicAdd(orow + 3, e * vv.w);
}

// out[r,:] /= denom[r]  (denom==0 -> 1). float4 per thread.
__global__ void normalize_kernel(float* __restrict__ out,
                                 const float* __restrict__ denom,
                                 int n_nodes) {
    int t = blockIdx.x * blockDim.x + threadIdx.x;         // one float4
    int total = n_nodes * (HD / 4);
    if (t >= total) return;
    int row = t >> 4;                                      // HD/4 == 16
    float d = denom[row];
    float inv = (d == 0.0f) ? 1.0f : __frcp_rn(d);
    float4* o4 = (float4*)out;
    float4 x = o4[t];
    x.x *= inv; x.y *= inv; x.z *= inv; x.w *= inv;
    o4[t] = x;
}

extern "C" void kernel_launch(void* const* d_in, const int* in_sizes, int n_in,
                              void* d_out, int out_size, void* d_ws, size_t ws_size,
                              hipStream_t stream) {
    const float* q       = (const float*)d_in[0];
    const float* k       = (const float*)d_in[1];
    const float* v       = (const float*)d_in[2];
    const float* eigs    = (const float*)d_in[3];
    const float* lambda0 = (const float*)d_in[4];
    const int*   idx     = (const int*)d_in[5];   // [2, E], int32

    const int n_edges = in_sizes[5] / 2;
    const int n_nodes = in_sizes[0] / HD;

    float* denom = (float*)d_ws;          // [N]

    hipMemsetAsync(denom, 0, (size_t)n_nodes * sizeof(float), stream);
    hipMemsetAsync(d_out, 0, (size_t)out_size * sizeof(float), stream);

    const int block = 256;  // 4 waves/block, 16 edges/block
    long long threads = (long long)n_edges * 16;
    int grid = (int)((threads + block - 1) / block);

    edge_fused_kernel<<<grid, block, 0, stream>>>(q, k, v, eigs, lambda0, idx,
                                                  denom, (float*)d_out, n_edges);

    int n4 = n_nodes * (HD / 4);
    normalize_kernel<<<(n4 + 255) / 256, 256, 0, stream>>>((float*)d_out, denom,
                                                           n_nodes);
}

// Round 4
// 543.874 us; speedup vs baseline: 2.9079x; 2.9079x over previous
//
#include <hip/hip_runtime.h>

// Sparse graph attention (fp32), fused edge pass + node normalize.
// 4 edges per 64-lane wave:
//   LOGITS: 16 lanes per edge. float4 q/k gathers (16B/lane), float2 eigs,
//           dot reduced over the 16-lane group via shfl_xor {8,4,2,1}.
//           e = min(exp(dot/8 + exp(l0)*eig_dot), 5); denom[i0] += e (sub==0).
//   SCATTER: loop j=0..3, FULL wave per edge (lane = channel):
//           one coalesced 256B v-load + ONE coalesced 256B atomic burst.
//           (Round-3 lesson: scalar 4x-atomics dirty 16B sectors -> 3.7x
//            WRITE_SIZE and vmcnt stalls. Keep the wave-contiguous burst.)
// then out[r,:] /= (denom[r]==0 ? 1 : denom[r]).

#define HD 64
#define ED 32

__global__ void edge_fused_kernel(const float* __restrict__ q,
                                  const float* __restrict__ k,
                                  const float* __restrict__ v,
                                  const float* __restrict__ eigs,
                                  const float* __restrict__ lambda0,
                                  const int* __restrict__ idx,
                                  float* __restrict__ denom,
                                  float* __restrict__ out,
                                  int n_edges) {
    long long gid = (long long)blockIdx.x * blockDim.x + threadIdx.x;
    int lane = threadIdx.x & 63;       // lane within wave
    int edge = (int)(gid >> 4);        // 16 lanes per edge (4 edges/wave)
    int sub  = (int)(gid & 15);

    int valid = (edge < n_edges);
    int ec = valid ? edge : (n_edges - 1);   // clamp for safe loads

    int i0 = idx[ec];            // destination (row)
    int i1 = idx[n_edges + ec];  // source (col)

    const float expL = __expf(lambda0[0]);

    // ---- logits: 16B vector gathers ----
    const float4* q4 = (const float4*)(q + (long long)i0 * HD);
    const float4* k4 = (const float4*)(k + (long long)i1 * HD);
    float4 qa = q4[sub];
    float4 kb = k4[sub];
    float c = qa.x * kb.x + qa.y * kb.y + qa.z * kb.z + qa.w * kb.w;
    c *= 0.125f;   // 1/sqrt(64)

    const float2* ea2 = (const float2*)(eigs + (long long)i0 * ED);
    const float2* eb2 = (const float2*)(eigs + (long long)i1 * ED);
    float2 ea = ea2[sub];
    float2 eb = eb2[sub];
    c += expL * (ea.x * eb.x + ea.y * eb.y);

    // reduce within the 16-lane group
    #pragma unroll
    for (int off = 8; off > 0; off >>= 1)
        c += __shfl_xor(c, off, 64);

    float e = fminf(__expf(c), 5.0f);   // exp>0, only upper clip binds

    if (valid && sub == 0) atomicAdd(&denom[i0], e);

    // ---- scatter: full wave per edge, one 256B atomic burst each ----
    #pragma unroll
    for (int j = 0; j < 4; ++j) {
        float ej = __shfl(e,     j * 16, 64);
        int   r  = __shfl(i0,    j * 16, 64);
        int   s  = __shfl(i1,    j * 16, 64);
        int   vj = __shfl(valid, j * 16, 64);
        if (vj) {
            float vv = v[(long long)s * HD + lane];   // coalesced 256B
            atomicAdd(&out[(long long)r * HD + lane], ej * vv);  // merged burst
        }
    }
}

// out[r,:] /= denom[r]  (denom==0 -> 1). float4 per thread.
__global__ void normalize_kernel(float* __restrict__ out,
                                 const float* __restrict__ denom,
                                 int n_nodes) {
    int t = blockIdx.x * blockDim.x + threadIdx.x;         // one float4
    int total = n_nodes * (HD / 4);
    if (t >= total) return;
    int row = t >> 4;                                      // HD/4 == 16
    float d = denom[row];
    float inv = (d == 0.0f) ? 1.0f : __frcp_rn(d);
    float4* o4 = (float4*)out;
    float4 x = o4[t];
    x.x *= inv; x.y *= inv; x.z *= inv; x.w *= inv;
    o4[t] = x;
}

extern "C" void kernel_launch(void* const* d_in, const int* in_sizes, int n_in,
                              void* d_out, int out_size, void* d_ws, size_t ws_size,
                              hipStream_t stream) {
    const float* q       = (const float*)d_in[0];
    const float* k       = (const float*)d_in[1];
    const float* v       = (const float*)d_in[2];
    const float* eigs    = (const float*)d_in[3];
    const float* lambda0 = (const float*)d_in[4];
    const int*   idx     = (const int*)d_in[5];   // [2, E], int32

    const int n_edges = in_sizes[5] / 2;
    const int n_nodes = in_sizes[0] / HD;

    float* denom = (float*)d_ws;          // [N]

    hipMemsetAsync(denom, 0, (size_t)n_nodes * sizeof(float), stream);
    hipMemsetAsync(d_out, 0, (size_t)out_size * sizeof(float), stream);

    const int block = 256;  // 4 waves/block, 16 edges/block
    long long threads = (long long)n_edges * 16;
    int grid = (int)((threads + block - 1) / block);

    edge_fused_kernel<<<grid, block, 0, stream>>>(q, k, v, eigs, lambda0, idx,
                                                  denom, (float*)d_out, n_edges);

    int n4 = n_nodes * (HD / 4);
    normalize_kernel<<<(n4 + 255) / 256, 256, 0, stream>>>((float*)d_out, denom,
                                                           n_nodes);
}

// Round 5
// 539.759 us; speedup vs baseline: 2.9301x; 1.0076x over previous
//
#include <hip/hip_runtime.h>

// Sparse graph attention (fp32), fused edge pass + node normalize.
// 8 edges per 64-lane wave, two 4-edge passes, ALL loads hoisted for MLP:
//   idx loads (8 edges) -> issue q/k/eigs gathers for both passes (16B/lane)
//   AND all 8 full-wave v-row loads (256B bursts, i1 broadcast via shfl)
//   -> then shuffle-reduce both passes -> denom atomics -> 8 coalesced
//   256B atomic bursts into out (unnormalized).
// then out[r,:] /= (denom[r]==0 ? 1 : denom[r]).
//
// Round-3 lesson kept: scatter is always a full-wave contiguous atomic burst
// (scalar per-lane multi-atomics dirty 16B sectors -> 3.7x WRITE_SIZE).
// Round-4 lesson: latency-bound, ~6 loads in flight per wave; this version
// holds ~16 outstanding loads per lane before the first dependent use.

#define HD 64
#define ED 32
#define EPW 8   // edges per wave

__global__ void edge_fused_kernel(const float* __restrict__ q,
                                  const float* __restrict__ k,
                                  const float* __restrict__ v,
                                  const float* __restrict__ eigs,
                                  const float* __restrict__ lambda0,
                                  const int* __restrict__ idx,
                                  float* __restrict__ denom,
                                  float* __restrict__ out,
                                  int n_edges) {
    long long tid  = (long long)blockIdx.x * blockDim.x + threadIdx.x;
    long long wave = tid >> 6;
    int lane = threadIdx.x & 63;
    int sub  = lane & 15;        // lane within 16-lane edge group
    int grp  = lane >> 4;        // which of 4 edge groups

    long long base = wave * EPW;
    if (base >= n_edges) return;

    const float expL = __expf(lambda0[0]);

    // ---- indices for both passes (edge = base + pass*4 + grp) ----
    int eA = (int)base + grp;        // pass 0
    int eB = (int)base + 4 + grp;    // pass 1
    int vA = (eA < n_edges), vB = (eB < n_edges);
    int ecA = vA ? eA : (n_edges - 1);
    int ecB = vB ? eB : (n_edges - 1);
    int i0a = idx[ecA], i1a = idx[n_edges + ecA];
    int i0b = idx[ecB], i1b = idx[n_edges + ecB];

    // ---- issue ALL q/k/eigs gathers (8 vector loads/lane) ----
    float4 qa0 = *(const float4*)(q    + (long long)i0a * HD + sub * 4);
    float4 kb0 = *(const float4*)(k    + (long long)i1a * HD + sub * 4);
    float2 ea0 = *(const float2*)(eigs + (long long)i0a * ED + sub * 2);
    float2 eb0 = *(const float2*)(eigs + (long long)i1a * ED + sub * 2);
    float4 qa1 = *(const float4*)(q    + (long long)i0b * HD + sub * 4);
    float4 kb1 = *(const float4*)(k    + (long long)i1b * HD + sub * 4);
    float2 ea1 = *(const float2*)(eigs + (long long)i0b * ED + sub * 2);
    float2 eb1 = *(const float2*)(eigs + (long long)i1b * ED + sub * 2);

    // ---- issue ALL 8 v-row loads (full-wave 256B bursts), independent of
    //      the reductions. i1 broadcast from the group's lane 0. ----
    float vv[EPW];
    int   rj[EPW];   // destination rows for scatter
    int   fj[EPW];   // validity
    #pragma unroll
    for (int j = 0; j < EPW; ++j) {
        int s = __shfl((j < 4) ? i1a : i1b, (j & 3) * 16, 64);
        rj[j] = __shfl((j < 4) ? i0a : i0b, (j & 3) * 16, 64);
        fj[j] = __shfl((j < 4) ? vA  : vB,  (j & 3) * 16, 64);
        vv[j] = v[(long long)s * HD + lane];   // clamped index -> safe
    }

    // ---- reductions (both passes interleave; loads already in flight) ----
    float c0 = (qa0.x * kb0.x + qa0.y * kb0.y + qa0.z * kb0.z + qa0.w * kb0.w)
               * 0.125f + expL * (ea0.x * eb0.x + ea0.y * eb0.y);
    float c1 = (qa1.x * kb1.x + qa1.y * kb1.y + qa1.z * kb1.z + qa1.w * kb1.w)
               * 0.125f + expL * (ea1.x * eb1.x + ea1.y * eb1.y);
    #pragma unroll
    for (int off = 8; off > 0; off >>= 1) {
        c0 += __shfl_xor(c0, off, 64);
        c1 += __shfl_xor(c1, off, 64);
    }
    float E0 = fminf(__expf(c0), 5.0f);   // exp>0, only upper clip binds
    float E1 = fminf(__expf(c1), 5.0f);

    if (sub == 0) {
        if (vA) atomicAdd(&denom[i0a], E0);
        if (vB) atomicAdd(&denom[i0b], E1);
    }

    // ---- scatter: 8 coalesced 256B atomic bursts ----
    #pragma unroll
    for (int j = 0; j < EPW; ++j) {
        float Ej = __shfl((j < 4) ? E0 : E1, (j & 3) * 16, 64);
        if (fj[j])
            atomicAdd(&out[(long long)rj[j] * HD + lane], Ej * vv[j]);
    }
}

// out[r,:] /= denom[r]  (denom==0 -> 1). float4 per thread.
__global__ void normalize_kernel(float* __restrict__ out,
                                 const float* __restrict__ denom,
                                 int n_nodes) {
    int t = blockIdx.x * blockDim.x + threadIdx.x;         // one float4
    int total = n_nodes * (HD / 4);
    if (t >= total) return;
    int row = t >> 4;                                      // HD/4 == 16
    float d = denom[row];
    float inv = (d == 0.0f) ? 1.0f : __frcp_rn(d);
    float4* o4 = (float4*)out;
    float4 x = o4[t];
    x.x *= inv; x.y *= inv; x.z *= inv; x.w *= inv;
    o4[t] = x;
}

extern "C" void kernel_launch(void* const* d_in, const int* in_sizes, int n_in,
                              void* d_out, int out_size, void* d_ws, size_t ws_size,
                              hipStream_t stream) {
    const float* q       = (const float*)d_in[0];
    const float* k       = (const float*)d_in[1];
    const float* v       = (const float*)d_in[2];
    const float* eigs    = (const float*)d_in[3];
    const float* lambda0 = (const float*)d_in[4];
    const int*   idx     = (const int*)d_in[5];   // [2, E], int32

    const int n_edges = in_sizes[5] / 2;
    const int n_nodes = in_sizes[0] / HD;

    float* denom = (float*)d_ws;          // [N]

    hipMemsetAsync(denom, 0, (size_t)n_nodes * sizeof(float), stream);
    hipMemsetAsync(d_out, 0, (size_t)out_size * sizeof(float), stream);

    const int block = 256;  // 4 waves/block, 32 edges/block
    long long waves = ((long long)n_edges + EPW - 1) / EPW;
    long long threads = waves * 64;
    int grid = (int)((threads + block - 1) / block);

    edge_fused_kernel<<<grid, block, 0, stream>>>(q, k, v, eigs, lambda0, idx,
                                                  denom, (float*)d_out, n_edges);

    int n4 = n_nodes * (HD / 4);
    normalize_kernel<<<(n4 + 255) / 256, 256, 0, stream>>>((float*)d_out, denom,
                                                           n_nodes);
}

// Round 6
// 449.837 us; speedup vs baseline: 3.5158x; 1.1999x over previous
//
#include <hip/hip_runtime.h>

// Sparse graph attention (fp32). Per-launch CSR build (counting sort by
// destination row), then an atomic-free row kernel.
//
//   build:  counts[r] = degree; row_start = exclusive_scan(counts);
//           csr_col[row_start[r]..] = source nodes of r's edges
//   row:    one 64-lane wave per row r. q[r],eigs[r] loaded ONCE.
//           8 edges in flight per iteration (4 groups x 2), dot via
//           shfl_xor{8..1} within 16-lane groups, accumulate e and e*v[c]
//           in registers, then cross-group reduce, normalize inline,
//           ONE coalesced 256B store. No atomics, no out memset.
//
// Round-3 lesson: wide per-lane scatters dirty 16B sectors (3.7x WRITE).
// Round-5 lesson: edge-parallel layout is transaction-bound (767MB fetch +
// 450MB atomic write-through); CSR removes the q-regather and ALL RMWs.

#define HD 64
#define ED 32

// ---------------- CSR build ----------------
__global__ void hist_kernel(const int* __restrict__ idx, int* __restrict__ counts,
                            int n_edges) {
    int t = blockIdx.x * blockDim.x + threadIdx.x;
    if (t < n_edges) atomicAdd(&counts[idx[t]], 1);
}

// per-1024-block exclusive scan; block totals -> sums
__global__ void scan_block_kernel(const int* __restrict__ counts,
                                  int* __restrict__ row_start,
                                  int* __restrict__ sums, int n) {
    __shared__ int wsum[16];
    int gid  = blockIdx.x * 1024 + threadIdx.x;
    int lane = threadIdx.x & 63;
    int wid  = threadIdx.x >> 6;
    int val = (gid < n) ? counts[gid] : 0;
    int x = val;
    #pragma unroll
    for (int off = 1; off < 64; off <<= 1) {
        int y = __shfl_up(x, off, 64);
        if (lane >= off) x += y;
    }
    if (lane == 63) wsum[wid] = x;
    __syncthreads();
    if (wid == 0 && lane < 16) {
        int s = wsum[lane];
        #pragma unroll
        for (int off = 1; off < 16; off <<= 1) {
            int y = __shfl_up(s, off, 64);
            if (lane >= off) s += y;
        }
        wsum[lane] = s;   // inclusive scan of wave totals
    }
    __syncthreads();
    int woff = (wid > 0) ? wsum[wid - 1] : 0;
    if (gid < n) row_start[gid] = x - val + woff;   // exclusive within block
    if (threadIdx.x == 0) sums[blockIdx.x] = wsum[15];
}

// exclusive scan of <=256 block sums, one 256-thread block
__global__ void scan_sums_kernel(int* __restrict__ sums, int nb) {
    __shared__ int wsum[4];
    int t = threadIdx.x, lane = t & 63, wid = t >> 6;
    int val = (t < nb) ? sums[t] : 0;
    int x = val;
    #pragma unroll
    for (int off = 1; off < 64; off <<= 1) {
        int y = __shfl_up(x, off, 64);
        if (lane >= off) x += y;
    }
    if (lane == 63) wsum[wid] = x;
    __syncthreads();
    if (t == 0) {
        int a = 0;
        #pragma unroll
        for (int i = 0; i < 4; ++i) { int b = wsum[i]; wsum[i] = a; a += b; }
    }
    __syncthreads();
    if (t < nb) sums[t] = x - val + wsum[wid];
}

__global__ void scan_add_kernel(int* __restrict__ row_start, int* __restrict__ cursor,
                                const int* __restrict__ sums, int n) {
    int gid = blockIdx.x * blockDim.x + threadIdx.x;
    if (gid < n) {
        int vv = row_start[gid] + sums[gid >> 10];
        row_start[gid] = vv;
        cursor[gid] = vv;
    }
}

__global__ void scatter_kernel(const int* __restrict__ idx, int* __restrict__ cursor,
                               int* __restrict__ col, int n_edges) {
    int t = blockIdx.x * blockDim.x + threadIdx.x;
    if (t < n_edges) {
        int r = idx[t];
        int c = idx[n_edges + t];
        int p = atomicAdd(&cursor[r], 1);
        col[p] = c;
    }
}

// ---------------- row kernel ----------------
__global__ void row_kernel(const float* __restrict__ q, const float* __restrict__ k,
                           const float* __restrict__ v, const float* __restrict__ eigs,
                           const float* __restrict__ lambda0,
                           const int* __restrict__ row_start,
                           const int* __restrict__ counts,
                           const int* __restrict__ col,
                           float* __restrict__ out, int n_nodes) {
    long long tid = (long long)blockIdx.x * blockDim.x + threadIdx.x;
    int r = (int)(tid >> 6);
    if (r >= n_nodes) return;
    int lane = threadIdx.x & 63;
    int sub = lane & 15;       // lane within 16-lane group (channel chunk)
    int grp = lane >> 4;       // edge slot within iteration

    int start = row_start[r];
    int deg   = counts[r];
    const float expL = __expf(lambda0[0]);

    float4 qa = *(const float4*)(q    + (long long)r * HD + sub * 4);
    float2 ga = *(const float2*)(eigs + (long long)r * ED + sub * 2);
    qa.x *= 0.125f; qa.y *= 0.125f; qa.z *= 0.125f; qa.w *= 0.125f;
    ga.x *= expL;   ga.y *= expL;

    float4 acc = make_float4(0.f, 0.f, 0.f, 0.f);
    float den = 0.f;

    for (int base = 0; base < deg; base += 64) {
        int m = deg - base; if (m > 64) m = 64;
        int cl = (lane < m) ? col[start + base + lane] : 0;  // 0 for pad slots
        for (int j = 0; j < m; j += 8) {
            // 8 edges: group grp takes j+grp and j+4+grp (pad -> row 0, masked)
            int c1 = __shfl(cl, j + grp,     64);
            int c2 = __shfl(cl, j + 4 + grp, 64);
            float4 kb1 = *(const float4*)(k    + (long long)c1 * HD + sub * 4);
            float2 gb1 = *(const float2*)(eigs + (long long)c1 * ED + sub * 2);
            float4 vv1 = *(const float4*)(v    + (long long)c1 * HD + sub * 4);
            float4 kb2 = *(const float4*)(k    + (long long)c2 * HD + sub * 4);
            float2 gb2 = *(const float2*)(eigs + (long long)c2 * ED + sub * 2);
            float4 vv2 = *(const float4*)(v    + (long long)c2 * HD + sub * 4);

            float s1 = qa.x*kb1.x + qa.y*kb1.y + qa.z*kb1.z + qa.w*kb1.w
                     + ga.x*gb1.x + ga.y*gb1.y;
            float s2 = qa.x*kb2.x + qa.y*kb2.y + qa.z*kb2.z + qa.w*kb2.w
                     + ga.x*gb2.x + ga.y*gb2.y;
            #pragma unroll
            for (int off = 8; off > 0; off >>= 1) {
                s1 += __shfl_xor(s1, off, 64);
                s2 += __shfl_xor(s2, off, 64);
            }
            float e1 = fminf(__expf(s1), 5.0f);  // exp>0, upper clip binds
            float e2 = fminf(__expf(s2), 5.0f);

            if (j + grp < m) {
                den += e1;
                acc.x += e1 * vv1.x; acc.y += e1 * vv1.y;
                acc.z += e1 * vv1.z; acc.w += e1 * vv1.w;
            }
            if (j + 4 + grp < m) {
                den += e2;
                acc.x += e2 * vv2.x; acc.y += e2 * vv2.y;
                acc.z += e2 * vv2.z; acc.w += e2 * vv2.w;
            }
        }
    }

    // combine the 4 edge-groups (identical channel layout per group)
    #pragma unroll
    for (int off = 16; off < 64; off <<= 1) {
        acc.x += __shfl_xor(acc.x, off, 64);
        acc.y += __shfl_xor(acc.y, off, 64);
        acc.z += __shfl_xor(acc.z, off, 64);
        acc.w += __shfl_xor(acc.w, off, 64);
        den   += __shfl_xor(den,   off, 64);
    }

    if (grp == 0) {
        float inv = (den == 0.0f) ? 1.0f : __frcp_rn(den);
        float4 o = make_float4(acc.x * inv, acc.y * inv, acc.z * inv, acc.w * inv);
        *(float4*)(out + (long long)r * HD + sub * 4) = o;
    }
}

extern "C" void kernel_launch(void* const* d_in, const int* in_sizes, int n_in,
                              void* d_out, int out_size, void* d_ws, size_t ws_size,
                              hipStream_t stream) {
    const float* q       = (const float*)d_in[0];
    const float* k       = (const float*)d_in[1];
    const float* v       = (const float*)d_in[2];
    const float* eigs    = (const float*)d_in[3];
    const float* lambda0 = (const float*)d_in[4];
    const int*   idx     = (const int*)d_in[5];   // [2, E], int32

    const int n_edges = in_sizes[5] / 2;
    const int n_nodes = in_sizes[0] / HD;

    int* counts    = (int*)d_ws;              // [N]
    int* row_start = counts + n_nodes;        // [N]
    int* cursor    = row_start + n_nodes;     // [N]
    int* sums      = cursor + n_nodes;        // [256]
    int* csr_col   = sums + 256;              // [E]

    hipMemsetAsync(counts, 0, (size_t)n_nodes * sizeof(int), stream);

    int eb = (n_edges + 255) / 256;
    hist_kernel<<<eb, 256, 0, stream>>>(idx, counts, n_edges);

    int nb = (n_nodes + 1023) / 1024;         // 98 <= 256
    scan_block_kernel<<<nb, 1024, 0, stream>>>(counts, row_start, sums, n_nodes);
    scan_sums_kernel<<<1, 256, 0, stream>>>(sums, nb);
    scan_add_kernel<<<(n_nodes + 255) / 256, 256, 0, stream>>>(row_start, cursor,
                                                               sums, n_nodes);
    scatter_kernel<<<eb, 256, 0, stream>>>(idx, cursor, csr_col, n_edges);

    long long threads = (long long)n_nodes * 64;
    int rb = (int)((threads + 255) / 256);
    row_kernel<<<rb, 256, 0, stream>>>(q, k, v, eigs, lambda0, row_start, counts,
                                       csr_col, (float*)d_out, n_nodes);
}

// Round 7
// 378.602 us; speedup vs baseline: 4.1773x; 1.1882x over previous
//
#include <hip/hip_runtime.h>

// Sparse graph attention (fp32). Build: direct fixed-capacity per-row buckets
// (NO counting sort / scan — round-6 lesson: CSR build cost 304us vs 146us
// compute). Then the atomic-free row kernel from round 6.
//
//   scatter: pos = atomicAdd(count[r],1); if (pos<CAP) bucket[r*CAP+pos]=c
//   row:     one 64-lane wave per row r. q[r],eigs[r] loaded ONCE. 8 edges
//            in flight per iteration, dot via shfl_xor within 16-lane groups,
//            normalize inline, ONE coalesced 256B store. No out atomics.
//   deg>CAP (P~3e-22/row here): wave rescans the edge list — correct always,
//            free when it never triggers.
//
// ws_size < 26MB -> fall back to the round-6 counting-sort CSR path
// (deterministic decision per problem, graph-capture safe).

#define HD 64
#define ED 32
#define CAP 64

// ---------------- bucket build ----------------
__global__ void bucket_scatter_kernel(const int* __restrict__ idx,
                                      int* __restrict__ count,
                                      int* __restrict__ bucket, int n_edges) {
    int t = blockIdx.x * blockDim.x + threadIdx.x;
    if (t < n_edges) {
        int r = idx[t];
        int c = idx[n_edges + t];
        int p = atomicAdd(&count[r], 1);
        if (p < CAP) bucket[(long long)r * CAP + p] = c;
    }
}

// ---------------- CSR build (fallback path only) ----------------
__global__ void hist_kernel(const int* __restrict__ idx, int* __restrict__ counts,
                            int n_edges) {
    int t = blockIdx.x * blockDim.x + threadIdx.x;
    if (t < n_edges) atomicAdd(&counts[idx[t]], 1);
}

__global__ void scan_block_kernel(const int* __restrict__ counts,
                                  int* __restrict__ row_start,
                                  int* __restrict__ sums, int n) {
    __shared__ int wsum[16];
    int gid  = blockIdx.x * 1024 + threadIdx.x;
    int lane = threadIdx.x & 63;
    int wid  = threadIdx.x >> 6;
    int val = (gid < n) ? counts[gid] : 0;
    int x = val;
    #pragma unroll
    for (int off = 1; off < 64; off <<= 1) {
        int y = __shfl_up(x, off, 64);
        if (lane >= off) x += y;
    }
    if (lane == 63) wsum[wid] = x;
    __syncthreads();
    if (wid == 0 && lane < 16) {
        int s = wsum[lane];
        #pragma unroll
        for (int off = 1; off < 16; off <<= 1) {
            int y = __shfl_up(s, off, 64);
            if (lane >= off) s += y;
        }
        wsum[lane] = s;
    }
    __syncthreads();
    int woff = (wid > 0) ? wsum[wid - 1] : 0;
    if (gid < n) row_start[gid] = x - val + woff;
    if (threadIdx.x == 0) sums[blockIdx.x] = wsum[15];
}

__global__ void scan_sums_kernel(int* __restrict__ sums, int nb) {
    __shared__ int wsum[4];
    int t = threadIdx.x, lane = t & 63, wid = t >> 6;
    int val = (t < nb) ? sums[t] : 0;
    int x = val;
    #pragma unroll
    for (int off = 1; off < 64; off <<= 1) {
        int y = __shfl_up(x, off, 64);
        if (lane >= off) x += y;
    }
    if (lane == 63) wsum[wid] = x;
    __syncthreads();
    if (t == 0) {
        int a = 0;
        #pragma unroll
        for (int i = 0; i < 4; ++i) { int b = wsum[i]; wsum[i] = a; a += b; }
    }
    __syncthreads();
    if (t < nb) sums[t] = x - val + wsum[wid];
}

__global__ void scan_add_kernel(int* __restrict__ row_start, int* __restrict__ cursor,
                                const int* __restrict__ sums, int n) {
    int gid = blockIdx.x * blockDim.x + threadIdx.x;
    if (gid < n) {
        int vv = row_start[gid] + sums[gid >> 10];
        row_start[gid] = vv;
        cursor[gid] = vv;
    }
}

__global__ void scatter_kernel(const int* __restrict__ idx, int* __restrict__ cursor,
                               int* __restrict__ col, int n_edges) {
    int t = blockIdx.x * blockDim.x + threadIdx.x;
    if (t < n_edges) {
        int r = idx[t];
        int c = idx[n_edges + t];
        int p = atomicAdd(&cursor[r], 1);
        col[p] = c;
    }
}

// ---------------- row kernel ----------------
template <bool BUCKET>
__global__ void row_kernel(const float* __restrict__ q, const float* __restrict__ k,
                           const float* __restrict__ v, const float* __restrict__ eigs,
                           const float* __restrict__ lambda0,
                           const int* __restrict__ row_start,
                           const int* __restrict__ counts,
                           const int* __restrict__ col,
                           const int* __restrict__ idx, int n_edges,
                           float* __restrict__ out, int n_nodes) {
    long long tid = (long long)blockIdx.x * blockDim.x + threadIdx.x;
    int r = (int)(tid >> 6);
    if (r >= n_nodes) return;
    int lane = threadIdx.x & 63;
    int sub = lane & 15;       // lane within 16-lane group (channel chunk)
    int grp = lane >> 4;       // edge slot within iteration

    int deg = counts[r];
    const float expL = __expf(lambda0[0]);

    if (BUCKET && deg > CAP) {
        // overflow slow path: rescan edge list (never triggers for this input)
        float qs = q[(long long)r * HD + lane] * 0.125f;
        float gs = (lane < ED) ? eigs[(long long)r * ED + lane] * expL : 0.f;
        float accs = 0.f, den = 0.f;
        for (int base = 0; base < n_edges; base += 64) {
            int e = base + lane;
            int rr = (e < n_edges) ? idx[e] : -1;
            int cc = (e < n_edges) ? idx[n_edges + e] : 0;
            unsigned long long mm = __ballot(rr == r);
            while (mm) {
                int b = __ffsll(mm) - 1;
                mm &= mm - 1;
                int c = __shfl(cc, b, 64);
                float kb = k[(long long)c * HD + lane];
                float gb = (lane < ED) ? eigs[(long long)c * ED + lane] : 0.f;
                float s = qs * kb + gs * gb;
                #pragma unroll
                for (int off = 32; off > 0; off >>= 1) s += __shfl_xor(s, off, 64);
                float e1 = fminf(__expf(s), 5.0f);
                den += e1;
                accs += e1 * v[(long long)c * HD + lane];
            }
        }
        float inv = (den == 0.f) ? 1.f : __frcp_rn(den);
        out[(long long)r * HD + lane] = accs * inv;
        return;
    }

    long long start = BUCKET ? (long long)r * CAP : (long long)row_start[r];

    float4 qa = *(const float4*)(q    + (long long)r * HD + sub * 4);
    float2 ga = *(const float2*)(eigs + (long long)r * ED + sub * 2);
    qa.x *= 0.125f; qa.y *= 0.125f; qa.z *= 0.125f; qa.w *= 0.125f;
    ga.x *= expL;   ga.y *= expL;

    float4 acc = make_float4(0.f, 0.f, 0.f, 0.f);
    float den = 0.f;

    for (int base = 0; base < deg; base += 64) {
        int m = deg - base; if (m > 64) m = 64;
        int cl = (lane < m) ? col[start + base + lane] : 0;  // pad -> row 0, masked
        for (int j = 0; j < m; j += 8) {
            int c1 = __shfl(cl, j + grp,     64);
            int c2 = __shfl(cl, j + 4 + grp, 64);
            float4 kb1 = *(const float4*)(k    + (long long)c1 * HD + sub * 4);
            float2 gb1 = *(const float2*)(eigs + (long long)c1 * ED + sub * 2);
            float4 vv1 = *(const float4*)(v    + (long long)c1 * HD + sub * 4);
            float4 kb2 = *(const float4*)(k    + (long long)c2 * HD + sub * 4);
            float2 gb2 = *(const float2*)(eigs + (long long)c2 * ED + sub * 2);
            float4 vv2 = *(const float4*)(v    + (long long)c2 * HD + sub * 4);

            float s1 = qa.x*kb1.x + qa.y*kb1.y + qa.z*kb1.z + qa.w*kb1.w
                     + ga.x*gb1.x + ga.y*gb1.y;
            float s2 = qa.x*kb2.x + qa.y*kb2.y + qa.z*kb2.z + qa.w*kb2.w
                     + ga.x*gb2.x + ga.y*gb2.y;
            #pragma unroll
            for (int off = 8; off > 0; off >>= 1) {
                s1 += __shfl_xor(s1, off, 64);
                s2 += __shfl_xor(s2, off, 64);
            }
            float e1 = fminf(__expf(s1), 5.0f);  // exp>0, upper clip binds
            float e2 = fminf(__expf(s2), 5.0f);

            if (j + grp < m) {
                den += e1;
                acc.x += e1 * vv1.x; acc.y += e1 * vv1.y;
                acc.z += e1 * vv1.z; acc.w += e1 * vv1.w;
            }
            if (j + 4 + grp < m) {
                den += e2;
                acc.x += e2 * vv2.x; acc.y += e2 * vv2.y;
                acc.z += e2 * vv2.z; acc.w += e2 * vv2.w;
            }
        }
    }

    #pragma unroll
    for (int off = 16; off < 64; off <<= 1) {
        acc.x += __shfl_xor(acc.x, off, 64);
        acc.y += __shfl_xor(acc.y, off, 64);
        acc.z += __shfl_xor(acc.z, off, 64);
        acc.w += __shfl_xor(acc.w, off, 64);
        den   += __shfl_xor(den,   off, 64);
    }

    if (grp == 0) {
        float inv = (den == 0.0f) ? 1.0f : __frcp_rn(den);
        float4 o = make_float4(acc.x * inv, acc.y * inv, acc.z * inv, acc.w * inv);
        *(float4*)(out + (long long)r * HD + sub * 4) = o;
    }
}

extern "C" void kernel_launch(void* const* d_in, const int* in_sizes, int n_in,
                              void* d_out, int out_size, void* d_ws, size_t ws_size,
                              hipStream_t stream) {
    const float* q       = (const float*)d_in[0];
    const float* k       = (const float*)d_in[1];
    const float* v       = (const float*)d_in[2];
    const float* eigs    = (const float*)d_in[3];
    const float* lambda0 = (const float*)d_in[4];
    const int*   idx     = (const int*)d_in[5];   // [2, E], int32

    const int n_edges = in_sizes[5] / 2;
    const int n_nodes = in_sizes[0] / HD;

    const int eb = (n_edges + 255) / 256;
    long long threads = (long long)n_nodes * 64;
    const int rb = (int)((threads + 255) / 256);

    size_t need_bucket = (size_t)n_nodes * sizeof(int)
                       + (size_t)n_nodes * CAP * sizeof(int);

    if (ws_size >= need_bucket) {
        // -------- fast path: direct buckets, 3 dispatches --------
        int* count  = (int*)d_ws;          // [N]
        int* bucket = count + n_nodes;     // [N*CAP]

        hipMemsetAsync(count, 0, (size_t)n_nodes * sizeof(int), stream);
        bucket_scatter_kernel<<<eb, 256, 0, stream>>>(idx, count, bucket, n_edges);
        row_kernel<true><<<rb, 256, 0, stream>>>(q, k, v, eigs, lambda0,
                                                 nullptr, count, bucket,
                                                 idx, n_edges,
                                                 (float*)d_out, n_nodes);
    } else {
        // -------- fallback: round-6 counting-sort CSR --------
        int* counts    = (int*)d_ws;              // [N]
        int* row_start = counts + n_nodes;        // [N]
        int* cursor    = row_start + n_nodes;     // [N]
        int* sums      = cursor + n_nodes;        // [256]
        int* csr_col   = sums + 256;              // [E]

        hipMemsetAsync(counts, 0, (size_t)n_nodes * sizeof(int), stream);
        hist_kernel<<<eb, 256, 0, stream>>>(idx, counts, n_edges);
        int nb = (n_nodes + 1023) / 1024;
        scan_block_kernel<<<nb, 1024, 0, stream>>>(counts, row_start, sums, n_nodes);
        scan_sums_kernel<<<1, 256, 0, stream>>>(sums, nb);
        scan_add_kernel<<<(n_nodes + 255) / 256, 256, 0, stream>>>(row_start, cursor,
                                                                   sums, n_nodes);
        scatter_kernel<<<eb, 256, 0, stream>>>(idx, cursor, csr_col, n_edges);
        row_kernel<false><<<rb, 256, 0, stream>>>(q, k, v, eigs, lambda0,
                                                  row_start, counts, csr_col,
                                                  idx, n_edges,
                                                  (float*)d_out, n_nodes);
    }
}

// Round 8
// 302.619 us; speedup vs baseline: 5.2261x; 1.2511x over previous
//
#include <hip/hip_runtime.h>

// Sparse graph attention (fp32).
// Build v3: hierarchical LDS-binned counting (rounds 6/7 lesson: random
// fetch-add + random 4B store runs at ~14-15G trans/s device-wide; the
// single-pass scatter was 1.6M+1.6M random transactions = ~225us).
//   p1: 256 blocks bin edges into NP=391 row-partitions (256 rows each) in
//       LDS (depth 36), pack (r&255)<<17|c in 4B, drain with ~100k global
//       atomics + contiguous bursts. Overflow -> spill list (unconditional
//       correctness; statistically ~0 entries).
//   p2: one workgroup per partition: LDS count[256] assigns row slots (LDS
//       atomics, ZERO fabric atomics), bucket stores land in a 64KB
//       L2-resident window (write-back, not fabric RMW). Counts written
//       coalesced for all rows (no count memset needed).
//   spill-drain + flag-gated repair kernels: all-exit when clean.
// Row kernel (unchanged, 147us): one wave per row, q/eigs loaded once,
// 8 edges in flight, one coalesced 256B store, no out atomics.
// Tiered ws fallback: >=35.2MB new path; >=26MB round-7 direct scatter;
// else round-4 fused atomic path.

#define HD 64
#define ED 32
#define CAP 64          // bucket slots per row
#define RPP 256         // rows per partition
#define PSHIFT 8
#define D1 36           // pass-1 LDS bin depth
#define NB1 256         // pass-1 blocks
#define PCAP 5120       // partition list capacity (mean 4093 at E=1.6M)
#define SPILL_CAP 131072

// ---------------- pass 1: partition binning ----------------
__global__ void p1_bin_kernel(const int* __restrict__ idx, int n_edges,
                              int NP, int chunk,
                              int* __restrict__ part, int* __restrict__ gcur,
                              long long* __restrict__ spill,
                              int* __restrict__ spill_cnt,
                              int* __restrict__ flag) {
    extern __shared__ int sm[];          // [NP] cnt, then [NP*D1] bins
    int* cnt  = sm;
    int* bins = sm + NP;
    int tid = threadIdx.x;

    for (int i = tid; i < NP; i += 256) cnt[i] = 0;
    __syncthreads();

    int e0 = blockIdx.x * chunk;
    int n  = n_edges - e0; if (n > chunk) n = chunk; if (n < 0) n = 0;

    for (int i = tid; i < n; i += 256) {
        int e = e0 + i;
        int r = idx[e];
        int c = idx[n_edges + e];
        int p = r >> PSHIFT;
        int w = ((r & (RPP - 1)) << 17) | c;
        int pos = atomicAdd(&cnt[p], 1);         // LDS atomic
        if (pos < D1) {
            bins[p * D1 + pos] = w;
        } else {                                 // statistical overflow
            int s = atomicAdd(spill_cnt, 1);
            if (s < SPILL_CAP) spill[s] = ((long long)r << 32) | (unsigned)c;
            else *flag = 1;
        }
    }
    __syncthreads();

    // drain: each thread owns a few bins; contiguous burst per bin
    for (int p = tid; p < NP; p += 256) {
        int m = cnt[p]; if (m > D1) m = D1;
        if (m > 0) {
            int base = atomicAdd(&gcur[p], m);
            for (int j = 0; j < m; ++j) {
                int slot = base + j;
                int w = bins[p * D1 + j];
                if (slot < PCAP) {
                    part[p * PCAP + slot] = w;
                } else {
                    int r = (p << PSHIFT) | (w >> 17);
                    int c = w & 0x1FFFF;
                    int s = atomicAdd(spill_cnt, 1);
                    if (s < SPILL_CAP) spill[s] = ((long long)r << 32) | (unsigned)c;
                    else *flag = 1;
                }
            }
        }
    }
}

// ---------------- pass 2: per-partition bucket fill ----------------
__global__ void p2_bucket_kernel(const int* __restrict__ part,
                                 const int* __restrict__ gcur,
                                 int* __restrict__ count,
                                 int* __restrict__ bucket, int n_nodes) {
    __shared__ int cnt[RPP];
    int tid = threadIdx.x;
    cnt[tid] = 0;
    __syncthreads();

    int p = blockIdx.x;
    int n = gcur[p]; if (n > PCAP) n = PCAP;

    for (int i = tid; i < n; i += 256) {
        int w  = part[p * PCAP + i];
        int rl = w >> 17;
        int c  = w & 0x1FFFF;
        int pos = atomicAdd(&cnt[rl], 1);        // LDS atomic
        if (pos < CAP) {
            long long r = (long long)((p << PSHIFT) + rl);
            bucket[r * CAP + pos] = c;           // L2-resident window store
        }
    }
    __syncthreads();

    int r = (p << PSHIFT) + tid;
    if (r < n_nodes) count[r] = cnt[tid];        // covers ALL rows (incl. 0)
}

// ---------------- spill drain (normally empty) ----------------
__global__ void spill_drain_kernel(const long long* __restrict__ spill,
                                   const int* __restrict__ spill_cnt,
                                   int* __restrict__ count,
                                   int* __restrict__ bucket) {
    int ns = *spill_cnt; if (ns > SPILL_CAP) ns = SPILL_CAP;
    int stride = gridDim.x * blockDim.x;
    for (int t = blockIdx.x * blockDim.x + threadIdx.x; t < ns; t += stride) {
        long long wc = spill[t];
        int r = (int)(wc >> 32);
        int c = (int)(wc & 0xFFFFFFFFLL);
        int pos = atomicAdd(&count[r], 1);
        if (pos < CAP) bucket[(long long)r * CAP + pos] = c;
    }
}

// ---------------- flag-gated repair (all-exit when clean) ----------------
__global__ void repair_zero_kernel(const int* __restrict__ flag,
                                   int* __restrict__ count, int n_nodes) {
    if (*flag == 0) return;
    int t = blockIdx.x * blockDim.x + threadIdx.x;
    if (t < n_nodes) count[t] = 0;
}

__global__ void repair_scatter_kernel(const int* __restrict__ flag,
                                      const int* __restrict__ idx,
                                      int* __restrict__ count,
                                      int* __restrict__ bucket, int n_edges) {
    if (*flag == 0) return;
    int t = blockIdx.x * blockDim.x + threadIdx.x;
    if (t < n_edges) {
        int r = idx[t];
        int c = idx[n_edges + t];
        int p = atomicAdd(&count[r], 1);
        if (p < CAP) bucket[(long long)r * CAP + p] = c;
    }
}

// ---------------- tier-2 build: direct scatter (round 7) ----------------
__global__ void bucket_scatter_kernel(const int* __restrict__ idx,
                                      int* __restrict__ count,
                                      int* __restrict__ bucket, int n_edges) {
    int t = blockIdx.x * blockDim.x + threadIdx.x;
    if (t < n_edges) {
        int r = idx[t];
        int c = idx[n_edges + t];
        int p = atomicAdd(&count[r], 1);
        if (p < CAP) bucket[(long long)r * CAP + p] = c;
    }
}

// ---------------- row kernel (round 7, unchanged) ----------------
__global__ void row_kernel(const float* __restrict__ q, const float* __restrict__ k,
                           const float* __restrict__ v, const float* __restrict__ eigs,
                           const float* __restrict__ lambda0,
                           const int* __restrict__ counts,
                           const int* __restrict__ col,
                           const int* __restrict__ idx, int n_edges,
                           float* __restrict__ out, int n_nodes) {
    long long tid = (long long)blockIdx.x * blockDim.x + threadIdx.x;
    int r = (int)(tid >> 6);
    if (r >= n_nodes) return;
    int lane = threadIdx.x & 63;
    int sub = lane & 15;
    int grp = lane >> 4;

    int deg = counts[r];
    const float expL = __expf(lambda0[0]);

    if (deg > CAP) {
        // overflow slow path: rescan edge list (never triggers for this input)
        float qs = q[(long long)r * HD + lane] * 0.125f;
        float gs = (lane < ED) ? eigs[(long long)r * ED + lane] * expL : 0.f;
        float accs = 0.f, den = 0.f;
        for (int base = 0; base < n_edges; base += 64) {
            int e = base + lane;
            int rr = (e < n_edges) ? idx[e] : -1;
            int cc = (e < n_edges) ? idx[n_edges + e] : 0;
            unsigned long long mm = __ballot(rr == r);
            while (mm) {
                int b = __ffsll(mm) - 1;
                mm &= mm - 1;
                int c = __shfl(cc, b, 64);
                float kb = k[(long long)c * HD + lane];
                float gb = (lane < ED) ? eigs[(long long)c * ED + lane] : 0.f;
                float s = qs * kb + gs * gb;
                #pragma unroll
                for (int off = 32; off > 0; off >>= 1) s += __shfl_xor(s, off, 64);
                float e1 = fminf(__expf(s), 5.0f);
                den += e1;
                accs += e1 * v[(long long)c * HD + lane];
            }
        }
        float inv = (den == 0.f) ? 1.f : __frcp_rn(den);
        out[(long long)r * HD + lane] = accs * inv;
        return;
    }

    long long start = (long long)r * CAP;

    float4 qa = *(const float4*)(q    + (long long)r * HD + sub * 4);
    float2 ga = *(const float2*)(eigs + (long long)r * ED + sub * 2);
    qa.x *= 0.125f; qa.y *= 0.125f; qa.z *= 0.125f; qa.w *= 0.125f;
    ga.x *= expL;   ga.y *= expL;

    float4 acc = make_float4(0.f, 0.f, 0.f, 0.f);
    float den = 0.f;

    for (int base = 0; base < deg; base += 64) {
        int m = deg - base; if (m > 64) m = 64;
        int cl = (lane < m) ? col[start + base + lane] : 0;
        for (int j = 0; j < m; j += 8) {
            int c1 = __shfl(cl, j + grp,     64);
            int c2 = __shfl(cl, j + 4 + grp, 64);
            float4 kb1 = *(const float4*)(k    + (long long)c1 * HD + sub * 4);
            float2 gb1 = *(const float2*)(eigs + (long long)c1 * ED + sub * 2);
            float4 vv1 = *(const float4*)(v    + (long long)c1 * HD + sub * 4);
            float4 kb2 = *(const float4*)(k    + (long long)c2 * HD + sub * 4);
            float2 gb2 = *(const float2*)(eigs + (long long)c2 * ED + sub * 2);
            float4 vv2 = *(const float4*)(v    + (long long)c2 * HD + sub * 4);

            float s1 = qa.x*kb1.x + qa.y*kb1.y + qa.z*kb1.z + qa.w*kb1.w
                     + ga.x*gb1.x + ga.y*gb1.y;
            float s2 = qa.x*kb2.x + qa.y*kb2.y + qa.z*kb2.z + qa.w*kb2.w
                     + ga.x*gb2.x + ga.y*gb2.y;
            #pragma unroll
            for (int off = 8; off > 0; off >>= 1) {
                s1 += __shfl_xor(s1, off, 64);
                s2 += __shfl_xor(s2, off, 64);
            }
            float e1 = fminf(__expf(s1), 5.0f);
            float e2 = fminf(__expf(s2), 5.0f);

            if (j + grp < m) {
                den += e1;
                acc.x += e1 * vv1.x; acc.y += e1 * vv1.y;
                acc.z += e1 * vv1.z; acc.w += e1 * vv1.w;
            }
            if (j + 4 + grp < m) {
                den += e2;
                acc.x += e2 * vv2.x; acc.y += e2 * vv2.y;
                acc.z += e2 * vv2.z; acc.w += e2 * vv2.w;
            }
        }
    }

    #pragma unroll
    for (int off = 16; off < 64; off <<= 1) {
        acc.x += __shfl_xor(acc.x, off, 64);
        acc.y += __shfl_xor(acc.y, off, 64);
        acc.z += __shfl_xor(acc.z, off, 64);
        acc.w += __shfl_xor(acc.w, off, 64);
        den   += __shfl_xor(den,   off, 64);
    }

    if (grp == 0) {
        float inv = (den == 0.0f) ? 1.0f : __frcp_rn(den);
        float4 o = make_float4(acc.x * inv, acc.y * inv, acc.z * inv, acc.w * inv);
        *(float4*)(out + (long long)r * HD + sub * 4) = o;
    }
}

// ---------------- tier-3: round-4 fused atomic path ----------------
__global__ void edge_fused_kernel(const float* __restrict__ q,
                                  const float* __restrict__ k,
                                  const float* __restrict__ v,
                                  const float* __restrict__ eigs,
                                  const float* __restrict__ lambda0,
                                  const int* __restrict__ idx,
                                  float* __restrict__ denom,
                                  float* __restrict__ out, int n_edges) {
    long long gid = (long long)blockIdx.x * blockDim.x + threadIdx.x;
    int lane = threadIdx.x & 63;
    int edge = (int)(gid >> 4);
    int sub  = (int)(gid & 15);
    int valid = (edge < n_edges);
    int ec = valid ? edge : (n_edges - 1);
    int i0 = idx[ec];
    int i1 = idx[n_edges + ec];
    const float expL = __expf(lambda0[0]);
    float4 qa = *(const float4*)(q + (long long)i0 * HD + sub * 4);
    float4 kb = *(const float4*)(k + (long long)i1 * HD + sub * 4);
    float c = (qa.x*kb.x + qa.y*kb.y + qa.z*kb.z + qa.w*kb.w) * 0.125f;
    float2 ea = *(const float2*)(eigs + (long long)i0 * ED + sub * 2);
    float2 eb = *(const float2*)(eigs + (long long)i1 * ED + sub * 2);
    c += expL * (ea.x * eb.x + ea.y * eb.y);
    #pragma unroll
    for (int off = 8; off > 0; off >>= 1) c += __shfl_xor(c, off, 64);
    float e = fminf(__expf(c), 5.0f);
    if (valid && sub == 0) atomicAdd(&denom[i0], e);
    #pragma unroll
    for (int j = 0; j < 4; ++j) {
        float ej = __shfl(e,     j * 16, 64);
        int   r  = __shfl(i0,    j * 16, 64);
        int   s  = __shfl(i1,    j * 16, 64);
        int   vj = __shfl(valid, j * 16, 64);
        if (vj) {
            float vv = v[(long long)s * HD + lane];
            atomicAdd(&out[(long long)r * HD + lane], ej * vv);
        }
    }
}

__global__ void normalize_kernel(float* __restrict__ out,
                                 const float* __restrict__ denom, int n_nodes) {
    int t = blockIdx.x * blockDim.x + threadIdx.x;
    int total = n_nodes * (HD / 4);
    if (t >= total) return;
    int row = t >> 4;
    float d = denom[row];
    float inv = (d == 0.0f) ? 1.0f : __frcp_rn(d);
    float4* o4 = (float4*)out;
    float4 x = o4[t];
    x.x *= inv; x.y *= inv; x.z *= inv; x.w *= inv;
    o4[t] = x;
}

extern "C" void kernel_launch(void* const* d_in, const int* in_sizes, int n_in,
                              void* d_out, int out_size, void* d_ws, size_t ws_size,
                              hipStream_t stream) {
    const float* q       = (const float*)d_in[0];
    const float* k       = (const float*)d_in[1];
    const float* v       = (const float*)d_in[2];
    const float* eigs    = (const float*)d_in[3];
    const float* lambda0 = (const float*)d_in[4];
    const int*   idx     = (const int*)d_in[5];   // [2, E], int32

    const int n_edges = in_sizes[5] / 2;
    const int n_nodes = in_sizes[0] / HD;

    const int NP = (n_nodes + RPP - 1) / RPP;
    const int eb = (n_edges + 255) / 256;
    long long rthreads = (long long)n_nodes * 64;
    const int rb = (int)((rthreads + 255) / 256);

    size_t need1 = ((size_t)n_nodes + (size_t)n_nodes * CAP
                    + (size_t)NP * PCAP + NP + 2) * sizeof(int)
                 + (size_t)SPILL_CAP * sizeof(long long);
    size_t need2 = ((size_t)n_nodes + (size_t)n_nodes * CAP) * sizeof(int);

    if (ws_size >= need1) {
        // -------- tier 1: LDS-binned two-pass build --------
        int* count     = (int*)d_ws;                    // [N]
        int* bucket    = count + n_nodes;               // [N*CAP]
        int* part      = bucket + (size_t)n_nodes * CAP;// [NP*PCAP]
        int* gcur      = part + (size_t)NP * PCAP;      // [NP]
        int* spill_cnt = gcur + NP;                     // [1]
        int* flag      = spill_cnt + 1;                 // [1]
        long long* spill = (long long*)(flag + 1);      // [SPILL_CAP]

        hipMemsetAsync(gcur, 0, (size_t)(NP + 2) * sizeof(int), stream);

        int chunk = (n_edges + NB1 - 1) / NB1;
        size_t smbytes = (size_t)NP * (1 + D1) * sizeof(int);
        p1_bin_kernel<<<NB1, 256, smbytes, stream>>>(idx, n_edges, NP, chunk,
                                                     part, gcur, spill,
                                                     spill_cnt, flag);
        p2_bucket_kernel<<<NP, 256, 0, stream>>>(part, gcur, count, bucket,
                                                 n_nodes);
        spill_drain_kernel<<<256, 256, 0, stream>>>(spill, spill_cnt, count,
                                                    bucket);
        repair_zero_kernel<<<(n_nodes + 255) / 256, 256, 0, stream>>>(flag, count,
                                                                      n_nodes);
        repair_scatter_kernel<<<eb, 256, 0, stream>>>(flag, idx, count, bucket,
                                                      n_edges);
        row_kernel<<<rb, 256, 0, stream>>>(q, k, v, eigs, lambda0, count, bucket,
                                           idx, n_edges, (float*)d_out, n_nodes);
    } else if (ws_size >= need2) {
        // -------- tier 2: direct scatter (round 7) --------
        int* count  = (int*)d_ws;
        int* bucket = count + n_nodes;
        hipMemsetAsync(count, 0, (size_t)n_nodes * sizeof(int), stream);
        bucket_scatter_kernel<<<eb, 256, 0, stream>>>(idx, count, bucket, n_edges);
        row_kernel<<<rb, 256, 0, stream>>>(q, k, v, eigs, lambda0, count, bucket,
                                           idx, n_edges, (float*)d_out, n_nodes);
    } else {
        // -------- tier 3: fused atomic path (round 4) --------
        float* denom = (float*)d_ws;   // [N]
        hipMemsetAsync(denom, 0, (size_t)n_nodes * sizeof(float), stream);
        hipMemsetAsync(d_out, 0, (size_t)out_size * sizeof(float), stream);
        long long threads = (long long)n_edges * 16;
        int grid = (int)((threads + 255) / 256);
        edge_fused_kernel<<<grid, 256, 0, stream>>>(q, k, v, eigs, lambda0, idx,
                                                    denom, (float*)d_out, n_edges);
        int n4 = n_nodes * (HD / 4);
        normalize_kernel<<<(n4 + 255) / 256, 256, 0, stream>>>((float*)d_out,
                                                               denom, n_nodes);
    }
}